// Round 2
// baseline (3354.700 us; speedup 1.0000x reference)
//
#include <hip/hip_runtime.h>

#define HH 128
#define TT 1024
#define NFUT 64
#define MB 2
#define NBLK 256
#define NITER (TT + NFUT)  // 1088 pipeline iterations

typedef _Float16 half8 __attribute__((ext_vector_type(8)));
typedef float floatx4 __attribute__((ext_vector_type(4)));

#define MFMA16(a, b, c) __builtin_amdgcn_mfma_f32_16x16x32_f16((a), (b), (c), 0, 0, 0)

__device__ __forceinline__ float sigm(float v) {
  return __builtin_amdgcn_rcpf(1.0f + __builtin_amdgcn_exp2f(v * -1.442695040888963f));
}
__device__ __forceinline__ float tanh_f(float v) {
  float a = __builtin_fabsf(v);
  float e = __builtin_amdgcn_exp2f(a * -2.885390081777927f);
  float r = (1.0f - e) * __builtin_amdgcn_rcpf(1.0f + e);
  return __builtin_copysignf(r, v);
}
__device__ __forceinline__ half8 ldw8(const float* __restrict__ p) {
  half8 r;
#pragma unroll
  for (int i = 0; i < 8; ++i) r[i] = (_Float16)p[i];
  return r;
}

// Persistent pipelined 2-layer LSTM. Grid 256 x 1024 threads (16 waves), MB=2
// batch rows per WG. Waves 0-7: cell1 (units 16w..16w+15). Waves 8-15: cell2.
// Iteration i: cell1 computes h1(i) while cell2 computes h2(i-1) -> one
// barrier per step (encoder); future phase adds a mid barrier for the
// out->x feedback. Weight B-fragments live in ONE shared array wf[8][4]
// (128 VGPRs) so both wave roles get the same allocation -> no spill.
__global__ __launch_bounds__(1024, 1) void lstm_kernel(
    const float* __restrict__ x,
    const float* __restrict__ W_ih1, const float* __restrict__ b_ih1,
    const float* __restrict__ W_hh1, const float* __restrict__ b_hh1,
    const float* __restrict__ W_ih2, const float* __restrict__ b_ih2,
    const float* __restrict__ W_hh2, const float* __restrict__ b_hh2,
    const float* __restrict__ W_out, const float* __restrict__ b_out,
    float* __restrict__ out)
{
  __shared__ __align__(16) _Float16 h1b[2][2048];  // A-frag order, rows>=MB stay 0
  __shared__ __align__(16) _Float16 h2b[2][2048];
  __shared__ __align__(16) _Float16 xs[TT * MB];   // [t][b] f16
  __shared__ float opart[8 * 4];                   // per-cell2-wave out partials

  const int tid = (int)threadIdx.x;
  const int lane = tid & 63;
  const int w = tid >> 6;
  const bool isC1 = (w < 8);
  const int nw = w & 7;            // unit-block index within role
  const int jl = lane & 15;
  const int rg = lane >> 4;
  const int j = nw * 16 + jl;      // hidden unit this lane owns (for B-frag/finalize)
  const int b0 = (int)blockIdx.x * MB;

  // ---- stage x -> LDS f16 [t][MB] (coalesced over t) ----
  for (int idx = tid; idx < TT * MB; idx += 1024) {
    int t = idx & (TT - 1);
    int bb = idx >> 10;
    xs[t * MB + bb] = (_Float16)x[(b0 + bb) * TT + t];
  }
  for (int idx = tid; idx < 2 * 2048; idx += 1024) {
    h1b[idx >> 11][idx & 2047] = (_Float16)0.0f;
    h2b[idx >> 11][idx & 2047] = (_Float16)0.0f;
  }

  // ---- weights -> shared VGPR array (role-dependent contents) ----
  half8 wf[8][4];
  float bias[4], wi1[4] = {0.f, 0.f, 0.f, 0.f};
  float wo = 0.f;
  if (isC1) {
#pragma unroll
    for (int q = 0; q < 4; ++q) {
#pragma unroll
      for (int kf = 0; kf < 4; ++kf)
        wf[q][kf] = ldw8(W_hh1 + (q * HH + j) * HH + kf * 32 + rg * 8);
      bias[q] = b_ih1[q * HH + j] + b_hh1[q * HH + j];
      wi1[q] = W_ih1[q * HH + j];
    }
  } else {
#pragma unroll
    for (int q = 0; q < 4; ++q) {
#pragma unroll
      for (int kf = 0; kf < 4; ++kf) {
        wf[q][kf]     = ldw8(W_hh2 + (q * HH + j) * HH + kf * 32 + rg * 8);
        wf[4 + q][kf] = ldw8(W_ih2 + (q * HH + j) * HH + kf * 32 + rg * 8);
      }
      bias[q] = b_ih2[q * HH + j] + b_hh2[q * HH + j];
    }
    wo = W_out[j];
  }
  const float bo = b_out[0];
  float c = 0.f;  // cell state for this lane's (row, unit)

  __syncthreads();

  const int aoff = lane * 8;  // A-frag ds_read element offset
  // h write slot for (row r=lane>>4, unit j), valid for lanes<32:
  const int wbase = ((j >> 5) << 9) + (((j >> 3) & 3) << 7) + (j & 7) + ((lane >> 4) << 3);

  for (int i = 0; i < NITER; ++i) {
    const int cur = i & 1;
    floatx4 acc[4] = {{0.f,0.f,0.f,0.f},{0.f,0.f,0.f,0.f},{0.f,0.f,0.f,0.f},{0.f,0.f,0.f,0.f}};

    if (isC1) {
      // ---- cell1 MFMA: gates(i) = h1(i-1) @ W_hh1^T  (x-term added later) ----
      if (i < NITER - 1) {
#pragma unroll
        for (int kf = 0; kf < 4; ++kf) {
          half8 av = *(const half8*)(&h1b[cur][kf * 512 + aoff]);
          acc[0] = MFMA16(av, wf[0][kf], acc[0]);
          acc[1] = MFMA16(av, wf[1][kf], acc[1]);
          acc[2] = MFMA16(av, wf[2][kf], acc[2]);
          acc[3] = MFMA16(av, wf[3][kf], acc[3]);
        }
      }
    } else if (i >= 1) {
      // ---- cell2 MFMA: gates(i-1) = h2(i-2)@W_hh2^T + h1(i-1)@W_ih2^T ----
#pragma unroll
      for (int kf = 0; kf < 4; ++kf) {
        half8 av = *(const half8*)(&h2b[cur][kf * 512 + aoff]);
        acc[0] = MFMA16(av, wf[0][kf], acc[0]);
        acc[1] = MFMA16(av, wf[1][kf], acc[1]);
        acc[2] = MFMA16(av, wf[2][kf], acc[2]);
        acc[3] = MFMA16(av, wf[3][kf], acc[3]);
      }
#pragma unroll
      for (int kf = 0; kf < 4; ++kf) {
        half8 av = *(const half8*)(&h1b[cur][kf * 512 + aoff]);
        acc[0] = MFMA16(av, wf[4][kf], acc[0]);
        acc[1] = MFMA16(av, wf[5][kf], acc[1]);
        acc[2] = MFMA16(av, wf[6][kf], acc[2]);
        acc[3] = MFMA16(av, wf[7][kf], acc[3]);
      }
      // ---- repack rows to lanes (16 units x 2 rows on lanes 0..31) ----
      float g[4];
#pragma unroll
      for (int q = 0; q < 4; ++q) {
        float t0 = __shfl(acc[q][0], jl);
        float t1 = __shfl(acc[q][1], jl);
        g[q] = (lane & 16) ? t1 : t0;
      }
      if (lane < 32) {
        float gi = g[0] + bias[0];
        float gf = g[1] + bias[1];
        float gg = g[2] + bias[2];
        float go = g[3] + bias[3];
        c = sigm(gf) * c + sigm(gi) * tanh_f(gg);
        float h = sigm(go) * tanh_f(c);
        h2b[cur ^ 1][wbase] = (_Float16)h;
        if (i >= TT) {  // projection partial for out(i-1)
          float p = h * wo;
          p += __shfl_xor(p, 1);
          p += __shfl_xor(p, 2);
          p += __shfl_xor(p, 4);
          p += __shfl_xor(p, 8);
          if (jl == 0) opart[nw * MB + (lane >> 4)] = p;
        }
      }
    }

    if (i >= TT) __syncthreads();  // publish opart (future-phase feedback)

    if (isC1) {
      float xv = 0.f;
      if (lane < 32) {
        if (i < TT) {
          xv = (float)xs[i * MB + (lane >> 4)];
        } else {
          float s = bo;
#pragma unroll
          for (int p8 = 0; p8 < 8; ++p8) s += opart[p8 * MB + (lane >> 4)];
          xv = s;
          if (w == 0 && jl == 0) out[(b0 + (lane >> 4)) * NFUT + (i - TT)] = s;
        }
      }
      if (i < NITER - 1) {
        float g[4];
#pragma unroll
        for (int q = 0; q < 4; ++q) {
          float t0 = __shfl(acc[q][0], jl);
          float t1 = __shfl(acc[q][1], jl);
          g[q] = (lane & 16) ? t1 : t0;
        }
        if (lane < 32) {
          float gi = g[0] + xv * wi1[0] + bias[0];
          float gf = g[1] + xv * wi1[1] + bias[1];
          float gg = g[2] + xv * wi1[2] + bias[2];
          float go = g[3] + xv * wi1[3] + bias[3];
          c = sigm(gf) * c + sigm(gi) * tanh_f(gg);
          float h = sigm(go) * tanh_f(c);
          h1b[cur ^ 1][wbase] = (_Float16)h;
        }
      }
    }
    __syncthreads();  // publish h1(i), h2(i-1)
  }
}

extern "C" void kernel_launch(void* const* d_in, const int* in_sizes, int n_in,
                              void* d_out, int out_size, void* d_ws, size_t ws_size,
                              hipStream_t stream) {
  const float* x     = (const float*)d_in[0];
  const float* W_ih1 = (const float*)d_in[1];
  const float* b_ih1 = (const float*)d_in[2];
  const float* W_hh1 = (const float*)d_in[3];
  const float* b_hh1 = (const float*)d_in[4];
  const float* W_ih2 = (const float*)d_in[5];
  const float* b_ih2 = (const float*)d_in[6];
  const float* W_hh2 = (const float*)d_in[7];
  const float* b_hh2 = (const float*)d_in[8];
  const float* W_out = (const float*)d_in[9];
  const float* b_out = (const float*)d_in[10];
  (void)in_sizes; (void)n_in; (void)out_size; (void)d_ws; (void)ws_size;

  lstm_kernel<<<dim3(NBLK), dim3(1024), 0, stream>>>(
      x, W_ih1, b_ih1, W_hh1, b_hh1, W_ih2, b_ih2, W_hh2, b_hh2, W_out, b_out,
      (float*)d_out);
}

// Round 5
// 1694.859 us; speedup vs baseline: 1.9793x; 1.9793x over previous
//
#include <hip/hip_runtime.h>

#define HH 128
#define TT 1024
#define NFUT 64
#define MB 2
#define NBLK 256
#define NITER (TT + NFUT - 1)  // 1087: i=1023 -> out[0], i=1086 -> out[63]

typedef _Float16 half8 __attribute__((ext_vector_type(8)));
typedef float floatx4 __attribute__((ext_vector_type(4)));

#define MFMA16(a, b, c) __builtin_amdgcn_mfma_f32_16x16x32_f16((a), (b), (c), 0, 0, 0)

__device__ __forceinline__ float sigm(float v) {
  return __builtin_amdgcn_rcpf(1.0f + __builtin_amdgcn_exp2f(v * -1.442695040888963f));
}
__device__ __forceinline__ float tanh_f(float v) {
  float a = __builtin_fabsf(v);
  float e = __builtin_amdgcn_exp2f(a * -2.885390081777927f);
  float r = (1.0f - e) * __builtin_amdgcn_rcpf(1.0f + e);
  return __builtin_copysignf(r, v);
}
__device__ __forceinline__ half8 ldw8(const float* __restrict__ p) {
  half8 r;
#pragma unroll
  for (int i = 0; i < 8; ++i) r[i] = (_Float16)p[i];
  return r;
}

// Persistent 2-layer LSTM. Grid 256 x 512 threads (8 waves), MB=2 rows/WG.
// Each wave owns units [16w,16w+16) of BOTH cells and holds 48 named half8
// weight B-fragments (192 regs). waves_per_eu(2,2) pins 2 waves/SIMD so the
// allocator gets the full 256-reg combined (VGPR+AGPR) budget and cannot
// squeeze-for-occupancy (the r1/r2 spill disease). Intrinsic MFMAs only ->
// hazard recognizer handles all wait-states (r3/r4 asm disease).
__global__
__attribute__((amdgpu_flat_work_group_size(512, 512), amdgpu_waves_per_eu(2, 2)))
void lstm_kernel(
    const float* __restrict__ x,
    const float* __restrict__ W_ih1, const float* __restrict__ b_ih1,
    const float* __restrict__ W_hh1, const float* __restrict__ b_hh1,
    const float* __restrict__ W_ih2, const float* __restrict__ b_ih2,
    const float* __restrict__ W_hh2, const float* __restrict__ b_hh2,
    const float* __restrict__ W_out, const float* __restrict__ b_out,
    float* __restrict__ out)
{
  __shared__ __align__(16) _Float16 h1b[2][2048];  // A-frag order; rows>=MB stay 0
  __shared__ __align__(16) _Float16 h2b[2][2048];
  __shared__ __align__(16) _Float16 xs[TT * MB];   // [t][b]
  __shared__ float opart[8 * MB];

  const int tid = (int)threadIdx.x;
  const int lane = tid & 63;
  const int w = tid >> 6;
  const int jl = lane & 15;
  const int rg = lane >> 4;
  const int j = w * 16 + jl;
  const int b0 = (int)blockIdx.x * MB;

  for (int idx = tid; idx < TT * MB; idx += 512) {
    int t = idx & (TT - 1);
    int bb = idx >> 10;
    xs[t * MB + bb] = (_Float16)x[(b0 + bb) * TT + t];
  }
  for (int idx = tid; idx < 2 * 2048; idx += 512) {
    h1b[idx >> 11][idx & 2047] = (_Float16)0.0f;
    h2b[idx >> 11][idx & 2047] = (_Float16)0.0f;
  }

  // ---- 48 named weight B-fragments: A=W_hh1, H=W_hh2, I=W_ih2 ----
  // B-frag: lane holds B[k=rg*8+i][n=jl] = W[q*HH + j][kf*32 + rg*8 + i]
  half8 A00, A01, A02, A03, A10, A11, A12, A13, A20, A21, A22, A23, A30, A31, A32, A33;
  half8 H00, H01, H02, H03, H10, H11, H12, H13, H20, H21, H22, H23, H30, H31, H32, H33;
  half8 I00, I01, I02, I03, I10, I11, I12, I13, I20, I21, I22, I23, I30, I31, I32, I33;
#define LDW(N, Q, P) do { \
    const float* _p = (P) + ((Q) * HH + j) * HH + rg * 8; \
    N##0 = ldw8(_p);      N##1 = ldw8(_p + 32); \
    N##2 = ldw8(_p + 64); N##3 = ldw8(_p + 96); } while (0)
  LDW(A0, 0, W_hh1); LDW(A1, 1, W_hh1); LDW(A2, 2, W_hh1); LDW(A3, 3, W_hh1);
  LDW(H0, 0, W_hh2); LDW(H1, 1, W_hh2); LDW(H2, 2, W_hh2); LDW(H3, 3, W_hh2);
  LDW(I0, 0, W_ih2); LDW(I1, 1, W_ih2); LDW(I2, 2, W_ih2); LDW(I3, 3, W_ih2);

  float bias1[4], bias2[4], wi1[4];
#pragma unroll
  for (int q = 0; q < 4; ++q) {
    bias1[q] = b_ih1[q * HH + j] + b_hh1[q * HH + j];
    bias2[q] = b_ih2[q * HH + j] + b_hh2[q * HH + j];
    wi1[q] = W_ih1[q * HH + j];
  }
  const float wo = W_out[j];
  const float bo = b_out[0];
  float c1 = 0.f, c2 = 0.f;

  __syncthreads();

  const int aoff = lane * 8;
  const int wbase = ((j >> 5) << 9) + (((j >> 3) & 3) << 7) + (j & 7) + (rg << 3);

#define G1K(KF) do { \
    half8 av = *(const half8*)(&h1b[cur][KF * 512 + aoff]); \
    acc0 = MFMA16(av, A0##KF, acc0); acc1 = MFMA16(av, A1##KF, acc1); \
    acc2 = MFMA16(av, A2##KF, acc2); acc3 = MFMA16(av, A3##KF, acc3); } while (0)
#define G2K(KF) do { \
    half8 av = *(const half8*)(&h2b[cur][KF * 512 + aoff]); \
    acc0 = MFMA16(av, H0##KF, acc0); acc1 = MFMA16(av, H1##KF, acc1); \
    acc2 = MFMA16(av, H2##KF, acc2); acc3 = MFMA16(av, H3##KF, acc3); \
    half8 aw = *(const half8*)(&h1b[nxt][KF * 512 + aoff]); \
    acc0 = MFMA16(aw, I0##KF, acc0); acc1 = MFMA16(aw, I1##KF, acc1); \
    acc2 = MFMA16(aw, I2##KF, acc2); acc3 = MFMA16(aw, I3##KF, acc3); } while (0)

  for (int i = 0; i < NITER; ++i) {
    const int cur = i & 1;
    const int nxt = cur ^ 1;

    // x input for this step (lanes<32: row rg<MB)
    float xv = 0.f;
    if (lane < 32) {
      if (i < TT) {
        xv = (float)xs[i * MB + rg];
      } else {
        float s = bo;
#pragma unroll
        for (int p8 = 0; p8 < 8; ++p8) s += opart[p8 * MB + rg];
        xv = s;
      }
    }

    // ---- phase 1: gates1 = h1(i-1) @ W_hh1^T ----
    floatx4 acc0 = {0.f,0.f,0.f,0.f}, acc1 = {0.f,0.f,0.f,0.f};
    floatx4 acc2 = {0.f,0.f,0.f,0.f}, acc3 = {0.f,0.f,0.f,0.f};
    G1K(0); G1K(1); G1K(2); G1K(3);
    {
      float t00 = __shfl(acc0[0], jl), t01 = __shfl(acc0[1], jl);
      float t10 = __shfl(acc1[0], jl), t11 = __shfl(acc1[1], jl);
      float t20 = __shfl(acc2[0], jl), t21 = __shfl(acc2[1], jl);
      float t30 = __shfl(acc3[0], jl), t31 = __shfl(acc3[1], jl);
      if (lane < 32) {
        float gi = ((lane & 16) ? t01 : t00) + xv * wi1[0] + bias1[0];
        float gf = ((lane & 16) ? t11 : t10) + xv * wi1[1] + bias1[1];
        float gg = ((lane & 16) ? t21 : t20) + xv * wi1[2] + bias1[2];
        float go = ((lane & 16) ? t31 : t30) + xv * wi1[3] + bias1[3];
        c1 = sigm(gf) * c1 + sigm(gi) * tanh_f(gg);
        float h = sigm(go) * tanh_f(c1);
        h1b[nxt][wbase] = (_Float16)h;
      }
    }
    __syncthreads();  // publish h1(i)

    // ---- phase 2: gates2 = h2(i-1) @ W_hh2^T + h1(i) @ W_ih2^T ----
    acc0 = (floatx4){0.f,0.f,0.f,0.f}; acc1 = (floatx4){0.f,0.f,0.f,0.f};
    acc2 = (floatx4){0.f,0.f,0.f,0.f}; acc3 = (floatx4){0.f,0.f,0.f,0.f};
    G2K(0); G2K(1); G2K(2); G2K(3);
    {
      float t00 = __shfl(acc0[0], jl), t01 = __shfl(acc0[1], jl);
      float t10 = __shfl(acc1[0], jl), t11 = __shfl(acc1[1], jl);
      float t20 = __shfl(acc2[0], jl), t21 = __shfl(acc2[1], jl);
      float t30 = __shfl(acc3[0], jl), t31 = __shfl(acc3[1], jl);
      if (lane < 32) {
        float gi = ((lane & 16) ? t01 : t00) + bias2[0];
        float gf = ((lane & 16) ? t11 : t10) + bias2[1];
        float gg = ((lane & 16) ? t21 : t20) + bias2[2];
        float go = ((lane & 16) ? t31 : t30) + bias2[3];
        c2 = sigm(gf) * c2 + sigm(gi) * tanh_f(gg);
        float h = sigm(go) * tanh_f(c2);
        h2b[nxt][wbase] = (_Float16)h;
        if (i >= TT - 1) {
          float p = h * wo;
          p += __shfl_xor(p, 1);
          p += __shfl_xor(p, 2);
          p += __shfl_xor(p, 4);
          p += __shfl_xor(p, 8);
          if (jl == 0) opart[w * MB + rg] = p;
        }
      }
    }
    __syncthreads();  // publish h2(i), opart(i)

    if (i >= TT - 1 && w == 0 && lane < MB) {
      float s = bo;
#pragma unroll
      for (int p8 = 0; p8 < 8; ++p8) s += opart[p8 * MB + lane];
      out[(b0 + lane) * NFUT + (i - (TT - 1))] = s;
    }
  }
}

extern "C" void kernel_launch(void* const* d_in, const int* in_sizes, int n_in,
                              void* d_out, int out_size, void* d_ws, size_t ws_size,
                              hipStream_t stream) {
  const float* x     = (const float*)d_in[0];
  const float* W_ih1 = (const float*)d_in[1];
  const float* b_ih1 = (const float*)d_in[2];
  const float* W_hh1 = (const float*)d_in[3];
  const float* b_hh1 = (const float*)d_in[4];
  const float* W_ih2 = (const float*)d_in[5];
  const float* b_ih2 = (const float*)d_in[6];
  const float* W_hh2 = (const float*)d_in[7];
  const float* b_hh2 = (const float*)d_in[8];
  const float* W_out = (const float*)d_in[9];
  const float* b_out = (const float*)d_in[10];
  (void)in_sizes; (void)n_in; (void)out_size; (void)d_ws; (void)ws_size;

  lstm_kernel<<<dim3(NBLK), dim3(512), 0, stream>>>(
      x, W_ih1, b_ih1, W_hh1, b_hh1, W_ih2, b_ih2, W_hh2, b_hh2, W_out, b_out,
      (float*)d_out);
}